// Round 1
// baseline (273.992 us; speedup 1.0000x reference)
//
#include <hip/hip_runtime.h>

// Problem constants
#define NTOK 2048     // B*T
#define DIMD 768
#define HD   3072
#define NE   4

typedef __bf16 bf16;
typedef __bf16 bf16x8 __attribute__((ext_vector_type(8)));
typedef float  f32x4  __attribute__((ext_vector_type(4)));

__device__ inline ushort f2bu(float f) {
  bf16 h = (bf16)f;
  ushort u;
  __builtin_memcpy(&u, &h, 2);
  return u;
}

// ---------------------------------------------------------------------------
// Router: one wave per token. Computes logits (4), softmax, top-2, weights,
// writes x as bf16, builds per-expert token lists via atomic counters.
// ---------------------------------------------------------------------------
__global__ __launch_bounds__(256) void k_router(
    const float* __restrict__ x, const float* __restrict__ rw,
    bf16* __restrict__ xb,
    float* __restrict__ probs, float* __restrict__ lse,
    int* __restrict__ tok_e, int* __restrict__ tok_slot,
    float* __restrict__ tok_w, int* __restrict__ list_tok,
    int* __restrict__ cnt)
{
  const int lane = threadIdx.x & 63;
  const int t = blockIdx.x * 4 + (threadIdx.x >> 6);

  const float4* xr = (const float4*)(x + (size_t)t * DIMD);
  const float4* w0 = (const float4*)(rw);
  const float4* w1 = (const float4*)(rw + DIMD);
  const float4* w2 = (const float4*)(rw + 2 * DIMD);
  const float4* w3 = (const float4*)(rw + 3 * DIMD);

  float a0 = 0.f, a1 = 0.f, a2 = 0.f, a3 = 0.f;
  float4 xv[3];
#pragma unroll
  for (int c = 0; c < 3; ++c) {
    float4 v = xr[lane + 64 * c];
    xv[c] = v;
    float4 q;
    q = w0[lane + 64 * c]; a0 += v.x*q.x + v.y*q.y + v.z*q.z + v.w*q.w;
    q = w1[lane + 64 * c]; a1 += v.x*q.x + v.y*q.y + v.z*q.z + v.w*q.w;
    q = w2[lane + 64 * c]; a2 += v.x*q.x + v.y*q.y + v.z*q.z + v.w*q.w;
    q = w3[lane + 64 * c]; a3 += v.x*q.x + v.y*q.y + v.z*q.z + v.w*q.w;
  }

  // store x as bf16 (coalesced 8B per lane per chunk)
  bf16* xo = xb + (size_t)t * DIMD;
#pragma unroll
  for (int c = 0; c < 3; ++c) {
    int d = 4 * (lane + 64 * c);
    ushort4 u;
    u.x = f2bu(xv[c].x); u.y = f2bu(xv[c].y);
    u.z = f2bu(xv[c].z); u.w = f2bu(xv[c].w);
    *(ushort4*)(xo + d) = u;
  }

#pragma unroll
  for (int s = 32; s > 0; s >>= 1) {
    a0 += __shfl_xor(a0, s);
    a1 += __shfl_xor(a1, s);
    a2 += __shfl_xor(a2, s);
    a3 += __shfl_xor(a3, s);
  }

  if (lane == 0) {
    float l[4] = {a0, a1, a2, a3};
    float m = fmaxf(fmaxf(l[0], l[1]), fmaxf(l[2], l[3]));
    float p[4];
    float s = 0.f;
#pragma unroll
    for (int e = 0; e < 4; ++e) { p[e] = expf(l[e] - m); s += p[e]; }
    float inv = 1.f / s;
#pragma unroll
    for (int e = 0; e < 4; ++e) p[e] *= inv;

    ((float4*)probs)[t] = make_float4(p[0], p[1], p[2], p[3]);
    lse[t] = m + logf(s);

    int i0 = 0;
#pragma unroll
    for (int e = 1; e < 4; ++e) if (l[e] > l[i0]) i0 = e;
    int i1 = -1;
#pragma unroll
    for (int e = 0; e < 4; ++e)
      if (e != i0 && (i1 < 0 || l[e] > l[i1])) i1 = e;

    float wsum = p[i0] + p[i1];
    tok_e[2 * t]     = i0;
    tok_e[2 * t + 1] = i1;
    tok_w[2 * t]     = p[i0] / wsum;
    tok_w[2 * t + 1] = p[i1] / wsum;

    int s0 = atomicAdd(&cnt[i0], 1);
    tok_slot[2 * t] = s0;
    list_tok[i0 * NTOK + s0] = t;
    int s1 = atomicAdd(&cnt[i1], 1);
    tok_slot[2 * t + 1] = s1;
    list_tok[i1 * NTOK + s1] = t;
  }
}

// ---------------------------------------------------------------------------
// Finalize: aux losses + exclusive scan of expert counts. Single block.
// ---------------------------------------------------------------------------
__global__ __launch_bounds__(256) void k_finalize(
    const float* __restrict__ probs, const float* __restrict__ lse,
    const int* __restrict__ cnt, int* __restrict__ base,
    float* __restrict__ out_tail)
{
  __shared__ float red[256];
  const int tid = threadIdx.x;
  float s0 = 0, s1 = 0, s2 = 0, s3 = 0, sz = 0;
  for (int t = tid; t < NTOK; t += 256) {
    float4 p = ((const float4*)probs)[t];
    s0 += p.x; s1 += p.y; s2 += p.z; s3 += p.w;
    float L = lse[t];
    sz += L * L;
  }
  float vals[5] = {s0, s1, s2, s3, sz};
  float res[5];
#pragma unroll
  for (int q = 0; q < 5; ++q) {
    __syncthreads();
    red[tid] = vals[q];
    __syncthreads();
    for (int s = 128; s > 0; s >>= 1) {
      if (tid < s) red[tid] += red[tid + s];
      __syncthreads();
    }
    res[q] = red[0];
  }
  if (tid == 0) {
    int c0 = cnt[0], c1 = cnt[1], c2 = cnt[2], c3 = cnt[3];
    float lb = (float)c0 * res[0] + (float)c1 * res[1] +
               (float)c2 * res[2] + (float)c3 * res[3];
    lb *= (float)NE / ((float)NTOK * (float)NTOK);
    out_tail[0] = lb;
    out_tail[1] = res[4] / (float)NTOK;
    base[0] = 0;
    base[1] = c0;
    base[2] = c0 + c1;
    base[3] = c0 + c1 + c2;
  }
}

// ---------------------------------------------------------------------------
// W_down combined = bf16(shared_down + routed_down[e]); layout [e][n=768][h=3072]
// ---------------------------------------------------------------------------
__global__ __launch_bounds__(256) void k_conv_dn(
    const float* __restrict__ sdn, const float* __restrict__ rdn,
    bf16* __restrict__ wdn)
{
  const int e = blockIdx.y;
  const int M = DIMD * HD / 4;
  const float4* s4 = (const float4*)sdn;
  const float4* r4 = (const float4*)(rdn + (size_t)e * DIMD * HD);
  ushort4* o4 = (ushort4*)(wdn + (size_t)e * DIMD * HD);
  for (int i = blockIdx.x * 256 + threadIdx.x; i < M; i += gridDim.x * 256) {
    float4 a = s4[i], b = r4[i];
    ushort4 u;
    u.x = f2bu(a.x + b.x);
    u.y = f2bu(a.y + b.y);
    u.z = f2bu(a.z + b.z);
    u.w = f2bu(a.w + b.w);
    o4[i] = u;
  }
}

// ---------------------------------------------------------------------------
// W_up combined, transposed: wupT[e][n=3072][d=768] = bf16(su[d][n]+ru[e][d][n])
// LDS 64x64 tile transpose, coalesced both sides.
// ---------------------------------------------------------------------------
__global__ __launch_bounds__(256) void k_conv_upT(
    const float* __restrict__ sup, const float* __restrict__ rup,
    bf16* __restrict__ wupT)
{
  __shared__ ushort T[64][72];   // 72-ushort rows: 144B, 16B-aligned, conflict-benign
  const int e = blockIdx.z;
  const int n0 = blockIdx.x * 64, d0 = blockIdx.y * 64;
  const int tid = threadIdx.x;
  const float* rb = rup + (size_t)e * DIMD * HD;
#pragma unroll
  for (int p = 0; p < 4; ++p) {
    int dl = p * 16 + (tid >> 4);
    int nl = (tid & 15) * 4;
    size_t gi = (size_t)(d0 + dl) * HD + (n0 + nl);
    float4 a = *(const float4*)(sup + gi);
    float4 b = *(const float4*)(rb + gi);
    T[nl + 0][dl] = f2bu(a.x + b.x);
    T[nl + 1][dl] = f2bu(a.y + b.y);
    T[nl + 2][dl] = f2bu(a.z + b.z);
    T[nl + 3][dl] = f2bu(a.w + b.w);
  }
  __syncthreads();
  bf16* ob = wupT + (size_t)e * HD * DIMD;
#pragma unroll
  for (int p = 0; p < 2; ++p) {
    int nl = p * 32 + (tid >> 3);
    int c = (tid & 7) * 8;
    uint4 v = *(const uint4*)&T[nl][c];
    *(uint4*)(ob + (size_t)(n0 + nl) * DIMD + d0 + c) = v;
  }
}

// ---------------------------------------------------------------------------
// Up GEMM: H[i][n] = sum_d X[tok(i)][d] * WupT[n][d]; epilogue relu^2 -> bf16.
// 128x128 tile, BK=32, 4 waves (64x64 each), mfma 16x16x32 bf16.
// ---------------------------------------------------------------------------
__global__ __launch_bounds__(256) void k_gemm_up(
    const bf16* __restrict__ xb, const bf16* __restrict__ wupT,
    const int* __restrict__ list_tok, const int* __restrict__ cnt,
    const int* __restrict__ base, bf16* __restrict__ hact)
{
  const int e = blockIdx.z;
  const int cn = cnt[e];
  const int m0 = blockIdx.y * 128;
  if (m0 >= cn) return;
  const int n0 = blockIdx.x * 128;

  __shared__ ushort As[128][40];   // 80B rows: stride-20-bank -> 2-way (free)
  __shared__ ushort Bs[128][40];

  const int tid = threadIdx.x;
  const int lane = tid & 63;
  const int wave = tid >> 6;
  const int wr = wave >> 1, wc = wave & 1;

  const bf16* Bb = wupT + (size_t)e * HD * DIMD;

  int lrow[2], lkc[2];
  bool av[2];
  const bf16* ap[2];
  const bf16* bp[2];
#pragma unroll
  for (int r = 0; r < 2; ++r) {
    int c = r * 256 + tid;          // 512 16B chunks per matrix
    int row = c >> 2, kc = c & 3;
    lrow[r] = row; lkc[r] = kc;
    int gr = m0 + row;
    av[r] = gr < cn;
    int tok = av[r] ? list_tok[e * NTOK + gr] : 0;
    ap[r] = xb + (size_t)tok * DIMD + kc * 8;
    bp[r] = Bb + (size_t)(n0 + row) * DIMD + kc * 8;
  }

  f32x4 acc[4][4] = {};
  uint4 ra[2], rb[2];
  const uint4 z4 = make_uint4(0, 0, 0, 0);

#define LOADT(kt) do { \
    ra[0] = av[0] ? *(const uint4*)(ap[0] + (kt) * 32) : z4; \
    ra[1] = av[1] ? *(const uint4*)(ap[1] + (kt) * 32) : z4; \
    rb[0] = *(const uint4*)(bp[0] + (kt) * 32); \
    rb[1] = *(const uint4*)(bp[1] + (kt) * 32); \
  } while (0)

  LOADT(0);
  const int NT = DIMD / 32;  // 24
  for (int kt = 0; kt < NT; ++kt) {
#pragma unroll
    for (int r = 0; r < 2; ++r) {
      *(uint4*)&As[lrow[r]][lkc[r] * 8] = ra[r];
      *(uint4*)&Bs[lrow[r]][lkc[r] * 8] = rb[r];
    }
    __syncthreads();
    if (kt + 1 < NT) LOADT(kt + 1);
    const int fr = lane & 15, ko = (lane >> 4) * 8;
    bf16x8 af[4], bq[4];
#pragma unroll
    for (int m = 0; m < 4; ++m) af[m] = *(const bf16x8*)&As[wr * 64 + m * 16 + fr][ko];
#pragma unroll
    for (int n = 0; n < 4; ++n) bq[n] = *(const bf16x8*)&Bs[wc * 64 + n * 16 + fr][ko];
#pragma unroll
    for (int m = 0; m < 4; ++m)
#pragma unroll
      for (int n = 0; n < 4; ++n)
        acc[m][n] = __builtin_amdgcn_mfma_f32_16x16x32_bf16(af[m], bq[n], acc[m][n], 0, 0, 0);
    __syncthreads();
  }
#undef LOADT

  const int ba = base[e];
  const int rg = (lane >> 4) * 4, cg = lane & 15;
#pragma unroll
  for (int m = 0; m < 4; ++m) {
#pragma unroll
    for (int q = 0; q < 4; ++q) {
      int row = m0 + wr * 64 + m * 16 + rg + q;
      if (row < cn) {
        bf16* orow = hact + (size_t)(ba + row) * HD + n0 + wc * 64 + cg;
#pragma unroll
        for (int n = 0; n < 4; ++n) {
          float h = acc[m][n][q];
          float rl = fmaxf(h, 0.f);
          orow[n * 16] = (bf16)(rl * rl);
        }
      }
    }
  }
}

// ---------------------------------------------------------------------------
// Down GEMM: Y[i][n] = sum_h Hact[i][h] * Wdn[n][h].  64x64 tile, BK=32,
// 4 waves (32x32 each) -> ~3 blocks/CU occupancy at per-expert M ~ 1024.
// ---------------------------------------------------------------------------
__global__ __launch_bounds__(256) void k_gemm_dn(
    const bf16* __restrict__ hact, const bf16* __restrict__ wdn,
    const int* __restrict__ cnt, const int* __restrict__ base,
    float* __restrict__ yc)
{
  const int e = blockIdx.z;
  const int cn = cnt[e];
  const int m0 = blockIdx.y * 64;
  if (m0 >= cn) return;
  const int n0 = blockIdx.x * 64;

  __shared__ ushort As[64][40];
  __shared__ ushort Bs[64][40];

  const int tid = threadIdx.x;
  const int lane = tid & 63, wave = tid >> 6;
  const int wr = wave >> 1, wc = wave & 1;
  const int ba = base[e];

  const bf16* Bb = wdn + (size_t)e * DIMD * HD;

  const int row = tid >> 2, kc = tid & 3;   // 256 16B chunks per matrix
  const int gr = m0 + row;
  const bool av = gr < cn;
  const bf16* ap = hact + (size_t)(ba + (av ? gr : 0)) * HD + kc * 8;
  const bf16* bp = Bb + (size_t)(n0 + row) * HD + kc * 8;

  f32x4 acc[2][2] = {};
  const uint4 z4 = make_uint4(0, 0, 0, 0);
  uint4 ra = av ? *(const uint4*)ap : z4;
  uint4 rb = *(const uint4*)bp;

  const int NT = HD / 32;  // 96
  for (int kt = 0; kt < NT; ++kt) {
    *(uint4*)&As[row][kc * 8] = ra;
    *(uint4*)&Bs[row][kc * 8] = rb;
    __syncthreads();
    if (kt + 1 < NT) {
      ra = av ? *(const uint4*)(ap + (kt + 1) * 32) : z4;
      rb = *(const uint4*)(bp + (kt + 1) * 32);
    }
    const int fr = lane & 15, ko = (lane >> 4) * 8;
    bf16x8 af[2], bq[2];
#pragma unroll
    for (int m = 0; m < 2; ++m) af[m] = *(const bf16x8*)&As[wr * 32 + m * 16 + fr][ko];
#pragma unroll
    for (int n = 0; n < 2; ++n) bq[n] = *(const bf16x8*)&Bs[wc * 32 + n * 16 + fr][ko];
#pragma unroll
    for (int m = 0; m < 2; ++m)
#pragma unroll
      for (int n = 0; n < 2; ++n)
        acc[m][n] = __builtin_amdgcn_mfma_f32_16x16x32_bf16(af[m], bq[n], acc[m][n], 0, 0, 0);
    __syncthreads();
  }

  const int rg = (lane >> 4) * 4, cg = lane & 15;
#pragma unroll
  for (int m = 0; m < 2; ++m) {
#pragma unroll
    for (int q = 0; q < 4; ++q) {
      int r2 = m0 + wr * 32 + m * 16 + rg + q;
      if (r2 < cn) {
        float* orow = yc + (size_t)(ba + r2) * DIMD + n0 + wc * 32 + cg;
#pragma unroll
        for (int n = 0; n < 2; ++n) orow[n * 16] = acc[m][n][q];
      }
    }
  }
}

// ---------------------------------------------------------------------------
// Combine: out[t] = w0 * yc[p0] + w1 * yc[p1]  (deterministic, no atomics)
// ---------------------------------------------------------------------------
__global__ __launch_bounds__(192) void k_combine(
    const float* __restrict__ yc, const int* __restrict__ tok_e,
    const int* __restrict__ tok_slot, const float* __restrict__ tok_w,
    const int* __restrict__ base, float* __restrict__ out)
{
  const int t = blockIdx.x;
  const int e0 = tok_e[2 * t], e1 = tok_e[2 * t + 1];
  const int p0 = base[e0] + tok_slot[2 * t];
  const int p1 = base[e1] + tok_slot[2 * t + 1];
  const float w0 = tok_w[2 * t], w1 = tok_w[2 * t + 1];
  const float4* a = (const float4*)(yc + (size_t)p0 * DIMD);
  const float4* b = (const float4*)(yc + (size_t)p1 * DIMD);
  float4* o = (float4*)(out + (size_t)t * DIMD);
  const int i = threadIdx.x;  // 192 threads * float4 = 768
  float4 va = a[i], vb = b[i];
  o[i] = make_float4(w0 * va.x + w1 * vb.x, w0 * va.y + w1 * vb.y,
                     w0 * va.z + w1 * vb.z, w0 * va.w + w1 * vb.w);
}

// ---------------------------------------------------------------------------
// Workspace layout (bytes; all offsets 256-aligned). Total ~78.8 MB.
// ---------------------------------------------------------------------------
extern "C" void kernel_launch(void* const* d_in, const int* in_sizes, int n_in,
                              void* d_out, int out_size, void* d_ws, size_t ws_size,
                              hipStream_t stream)
{
  const float* x   = (const float*)d_in[0];
  const float* rw  = (const float*)d_in[1];
  const float* sup = (const float*)d_in[2];
  const float* sdn = (const float*)d_in[3];
  const float* rup = (const float*)d_in[4];
  const float* rdn = (const float*)d_in[5];
  float* out = (float*)d_out;

  char* w = (char*)d_ws;
  bf16*  xb       = (bf16*)(w + 0);           //  3,145,728 B  [2048][768]
  bf16*  wupT     = (bf16*)(w + 3145728);     // 18,874,368 B  [4][3072][768]
  bf16*  wdn      = (bf16*)(w + 22020096);    // 18,874,368 B  [4][768][3072]
  bf16*  hact     = (bf16*)(w + 40894464);    // 25,165,824 B  [4096][3072]
  float* yc       = (float*)(w + 66060288);   // 12,582,912 B  [4096][768]
  float* probs    = (float*)(w + 78643200);   //     32,768 B  [2048][4]
  float* lse      = (float*)(w + 78675968);   //      8,192 B
  int*   tok_e    = (int*)(w + 78684160);     //     16,384 B  [2048][2]
  int*   tok_slot = (int*)(w + 78700544);     //     16,384 B
  float* tok_w    = (float*)(w + 78716928);   //     16,384 B
  int*   list_tok = (int*)(w + 78733312);     //     32,768 B  [4][2048]
  int*   cnt      = (int*)(w + 78766080);     //         16 B
  int*   base     = (int*)(w + 78766336);     //         16 B

  hipMemsetAsync(cnt, 0, 16, stream);

  k_router<<<512, 256, 0, stream>>>(x, rw, xb, probs, lse, tok_e, tok_slot,
                                    tok_w, list_tok, cnt);
  k_finalize<<<1, 256, 0, stream>>>(probs, lse, cnt, base,
                                    out + (size_t)NTOK * DIMD);
  k_conv_dn<<<dim3(576, 4), 256, 0, stream>>>(sdn, rdn, wdn);
  k_conv_upT<<<dim3(48, 12, 4), 256, 0, stream>>>(sup, rup, wupT);
  k_gemm_up<<<dim3(24, 16, 4), 256, 0, stream>>>(xb, wupT, list_tok, cnt, base, hact);
  k_gemm_dn<<<dim3(12, 32, 4), 256, 0, stream>>>(hact, wdn, cnt, base, yc);
  k_combine<<<2048, 192, 0, stream>>>(yc, tok_e, tok_slot, tok_w, base, out);
}

// Round 2
// 156.546 us; speedup vs baseline: 1.7502x; 1.7502x over previous
//
#include <hip/hip_runtime.h>

// Problem constants
#define NTOK 2048     // B*T
#define DIMD 768
#define HD   3072
#define NE   4

typedef __bf16 bf16;
typedef __bf16 bf16x8 __attribute__((ext_vector_type(8)));
typedef float  f32x4  __attribute__((ext_vector_type(4)));
typedef unsigned int u32;

__device__ inline ushort f2bu(float f) {
  bf16 h = (bf16)f;
  ushort u;
  __builtin_memcpy(&u, &h, 2);
  return u;
}

// async global->LDS, 16B per lane; lds ptr must be wave-uniform
__device__ __forceinline__ void gl16(const void* g, void* l) {
  __builtin_amdgcn_global_load_lds(
      (const __attribute__((address_space(1))) u32*)g,
      (__attribute__((address_space(3))) u32*)l, 16, 0, 0);
}

// ---------------------------------------------------------------------------
// Router: one wave per token. logits(4), softmax, top-2, x->bf16, expert lists.
// ---------------------------------------------------------------------------
__global__ __launch_bounds__(256) void k_router(
    const float* __restrict__ x, const float* __restrict__ rw,
    bf16* __restrict__ xb,
    float* __restrict__ probs, float* __restrict__ lse,
    int* __restrict__ tok_e, int* __restrict__ tok_slot,
    float* __restrict__ tok_w, int* __restrict__ list_tok,
    int* __restrict__ cnt)
{
  const int lane = threadIdx.x & 63;
  const int t = blockIdx.x * 4 + (threadIdx.x >> 6);

  const float4* xr = (const float4*)(x + (size_t)t * DIMD);
  const float4* w0 = (const float4*)(rw);
  const float4* w1 = (const float4*)(rw + DIMD);
  const float4* w2 = (const float4*)(rw + 2 * DIMD);
  const float4* w3 = (const float4*)(rw + 3 * DIMD);

  float a0 = 0.f, a1 = 0.f, a2 = 0.f, a3 = 0.f;
  float4 xv[3];
#pragma unroll
  for (int c = 0; c < 3; ++c) {
    float4 v = xr[lane + 64 * c];
    xv[c] = v;
    float4 q;
    q = w0[lane + 64 * c]; a0 += v.x*q.x + v.y*q.y + v.z*q.z + v.w*q.w;
    q = w1[lane + 64 * c]; a1 += v.x*q.x + v.y*q.y + v.z*q.z + v.w*q.w;
    q = w2[lane + 64 * c]; a2 += v.x*q.x + v.y*q.y + v.z*q.z + v.w*q.w;
    q = w3[lane + 64 * c]; a3 += v.x*q.x + v.y*q.y + v.z*q.z + v.w*q.w;
  }

  bf16* xo = xb + (size_t)t * DIMD;
#pragma unroll
  for (int c = 0; c < 3; ++c) {
    int d = 4 * (lane + 64 * c);
    ushort4 u;
    u.x = f2bu(xv[c].x); u.y = f2bu(xv[c].y);
    u.z = f2bu(xv[c].z); u.w = f2bu(xv[c].w);
    *(ushort4*)(xo + d) = u;
  }

#pragma unroll
  for (int s = 32; s > 0; s >>= 1) {
    a0 += __shfl_xor(a0, s);
    a1 += __shfl_xor(a1, s);
    a2 += __shfl_xor(a2, s);
    a3 += __shfl_xor(a3, s);
  }

  if (lane == 0) {
    float l[4] = {a0, a1, a2, a3};
    float m = fmaxf(fmaxf(l[0], l[1]), fmaxf(l[2], l[3]));
    float p[4];
    float s = 0.f;
#pragma unroll
    for (int e = 0; e < 4; ++e) { p[e] = expf(l[e] - m); s += p[e]; }
    float inv = 1.f / s;
#pragma unroll
    for (int e = 0; e < 4; ++e) p[e] *= inv;

    ((float4*)probs)[t] = make_float4(p[0], p[1], p[2], p[3]);
    lse[t] = m + logf(s);

    int i0 = 0;
#pragma unroll
    for (int e = 1; e < 4; ++e) if (l[e] > l[i0]) i0 = e;
    int i1 = -1;
#pragma unroll
    for (int e = 0; e < 4; ++e)
      if (e != i0 && (i1 < 0 || l[e] > l[i1])) i1 = e;

    float wsum = p[i0] + p[i1];
    tok_e[2 * t]     = i0;
    tok_e[2 * t + 1] = i1;
    tok_w[2 * t]     = p[i0] / wsum;
    tok_w[2 * t + 1] = p[i1] / wsum;

    int s0 = atomicAdd(&cnt[i0], 1);
    tok_slot[2 * t] = s0;
    list_tok[i0 * NTOK + s0] = t;
    int s1 = atomicAdd(&cnt[i1], 1);
    tok_slot[2 * t + 1] = s1;
    list_tok[i1 * NTOK + s1] = t;
  }
}

// ---------------------------------------------------------------------------
// Finalize: aux losses + exclusive scan of expert counts. Single block.
// ---------------------------------------------------------------------------
__global__ __launch_bounds__(256) void k_finalize(
    const float* __restrict__ probs, const float* __restrict__ lse,
    const int* __restrict__ cnt, int* __restrict__ base,
    float* __restrict__ out_tail)
{
  __shared__ float red[256];
  const int tid = threadIdx.x;
  float s0 = 0, s1 = 0, s2 = 0, s3 = 0, sz = 0;
  for (int t = tid; t < NTOK; t += 256) {
    float4 p = ((const float4*)probs)[t];
    s0 += p.x; s1 += p.y; s2 += p.z; s3 += p.w;
    float L = lse[t];
    sz += L * L;
  }
  float vals[5] = {s0, s1, s2, s3, sz};
  float res[5];
#pragma unroll
  for (int q = 0; q < 5; ++q) {
    __syncthreads();
    red[tid] = vals[q];
    __syncthreads();
    for (int s = 128; s > 0; s >>= 1) {
      if (tid < s) red[tid] += red[tid + s];
      __syncthreads();
    }
    res[q] = red[0];
  }
  if (tid == 0) {
    int c0 = cnt[0], c1 = cnt[1], c2 = cnt[2], c3 = cnt[3];
    float lb = (float)c0 * res[0] + (float)c1 * res[1] +
               (float)c2 * res[2] + (float)c3 * res[3];
    lb *= (float)NE / ((float)NTOK * (float)NTOK);
    out_tail[0] = lb;
    out_tail[1] = res[4] / (float)NTOK;
    base[0] = 0;
    base[1] = c0;
    base[2] = c0 + c1;
    base[3] = c0 + c1 + c2;
  }
}

// ---------------------------------------------------------------------------
// W_down combined = bf16(shared_down + routed_down[e]); [e][n=768][h=3072]
// ---------------------------------------------------------------------------
__global__ __launch_bounds__(256) void k_conv_dn(
    const float* __restrict__ sdn, const float* __restrict__ rdn,
    bf16* __restrict__ wdn)
{
  const int e = blockIdx.y;
  const int M = DIMD * HD / 4;
  const float4* s4 = (const float4*)sdn;
  const float4* r4 = (const float4*)(rdn + (size_t)e * DIMD * HD);
  ushort4* o4 = (ushort4*)(wdn + (size_t)e * DIMD * HD);
  for (int i = blockIdx.x * 256 + threadIdx.x; i < M; i += gridDim.x * 256) {
    float4 a = s4[i], b = r4[i];
    ushort4 u;
    u.x = f2bu(a.x + b.x);
    u.y = f2bu(a.y + b.y);
    u.z = f2bu(a.z + b.z);
    u.w = f2bu(a.w + b.w);
    o4[i] = u;
  }
}

// ---------------------------------------------------------------------------
// W_up combined, transposed: wupT[e][n=3072][d=768]
// ---------------------------------------------------------------------------
__global__ __launch_bounds__(256) void k_conv_upT(
    const float* __restrict__ sup, const float* __restrict__ rup,
    bf16* __restrict__ wupT)
{
  __shared__ ushort T[64][72];
  const int e = blockIdx.z;
  const int n0 = blockIdx.x * 64, d0 = blockIdx.y * 64;
  const int tid = threadIdx.x;
  const float* rb = rup + (size_t)e * DIMD * HD;
#pragma unroll
  for (int p = 0; p < 4; ++p) {
    int dl = p * 16 + (tid >> 4);
    int nl = (tid & 15) * 4;
    size_t gi = (size_t)(d0 + dl) * HD + (n0 + nl);
    float4 a = *(const float4*)(sup + gi);
    float4 b = *(const float4*)(rb + gi);
    T[nl + 0][dl] = f2bu(a.x + b.x);
    T[nl + 1][dl] = f2bu(a.y + b.y);
    T[nl + 2][dl] = f2bu(a.z + b.z);
    T[nl + 3][dl] = f2bu(a.w + b.w);
  }
  __syncthreads();
  bf16* ob = wupT + (size_t)e * HD * DIMD;
#pragma unroll
  for (int p = 0; p < 2; ++p) {
    int nl = p * 32 + (tid >> 3);
    int c = (tid & 7) * 8;
    uint4 v = *(const uint4*)&T[nl][c];
    *(uint4*)(ob + (size_t)(n0 + nl) * DIMD + d0 + c) = v;
  }
}

// ---------------------------------------------------------------------------
// Up GEMM: H[i][n] = sum_d X[tok(i)][d] * WupT[n][d]; relu^2 -> bf16 hact.
// 128x128 tile, BK=64, global_load_lds staging (linear dest, pre-swizzled
// source), XOR-swizzled ds_read_b128, double-buffered, 1 barrier / K-step.
// LDS-staged coalesced epilogue.
// ---------------------------------------------------------------------------
__global__ __launch_bounds__(256, 2) void k_gemm_up(
    const bf16* __restrict__ xb, const bf16* __restrict__ wupT,
    const int* __restrict__ list_tok, const int* __restrict__ cnt,
    const int* __restrict__ base, bf16* __restrict__ hact)
{
  const int e = blockIdx.z;
  const int cn = cnt[e];
  const int m0 = blockIdx.y * 128;
  if (m0 >= cn) return;
  const int n0 = blockIdx.x * 128;

  // buf b at b*32768: A tile [128][128B] then B tile [128][128B]
  __shared__ char lds[65536];

  const int tid = threadIdx.x;
  const int lane = tid & 63;
  const int wave = tid >> 6;
  const int wr = wave >> 1, wc = wave & 1;

  const bf16* Bb = wupT + (size_t)e * HD * DIMD;

  // staging sources (pre-swizzled chunk):  c = (lane&7) ^ (row&7), row&7 = lane>>3
  const int c16 = ((lane & 7) ^ (lane >> 3)) * 16;
  const char* apt[4];
  const char* bpt[4];
#pragma unroll
  for (int j = 0; j < 4; ++j) {
    int row = (wave * 4 + j) * 8 + (lane >> 3);
    int ar = m0 + row; if (ar > cn - 1) ar = cn - 1;
    int tok = list_tok[e * NTOK + ar];
    apt[j] = (const char*)(xb + (size_t)tok * DIMD) + c16;
    bpt[j] = (const char*)(Bb + (size_t)(n0 + row) * DIMD) + c16;
  }

  auto stage = [&](int b, int kt) {
    char* la = lds + b * 32768 + (wave * 4) * 1024;
    char* lb = la + 16384;
#pragma unroll
    for (int j = 0; j < 4; ++j) {
      gl16(apt[j] + kt * 128, la + j * 1024);
      gl16(bpt[j] + kt * 128, lb + j * 1024);
    }
  };

  f32x4 acc[4][4] = {};
  const int koff = lane >> 4;     // 16B slot within 32-k slice
  const int xr = lane & 7;        // read-side XOR (== row&7 of frag rows)
  const int fr = lane & 15;

  stage(0, 0);
  const int NT = DIMD * 2 / 128;  // 12
  int cur = 0;
  for (int kt = 0; kt < NT; ++kt) {
    __syncthreads();                       // buf[cur] staged; prev reads done
    if (kt + 1 < NT) stage(cur ^ 1, kt + 1);
    const char* Ab = lds + cur * 32768;
    const char* Bc = Ab + 16384;
#pragma unroll
    for (int ks = 0; ks < 2; ++ks) {
      const int sl = ((ks * 4 + koff) ^ xr) * 16;
      bf16x8 af[4], bq[4];
#pragma unroll
      for (int m = 0; m < 4; ++m)
        af[m] = *(const bf16x8*)(Ab + (wr * 64 + m * 16 + fr) * 128 + sl);
#pragma unroll
      for (int n = 0; n < 4; ++n)
        bq[n] = *(const bf16x8*)(Bc + (wc * 64 + n * 16 + fr) * 128 + sl);
#pragma unroll
      for (int m = 0; m < 4; ++m)
#pragma unroll
        for (int n = 0; n < 4; ++n)
          acc[m][n] = __builtin_amdgcn_mfma_f32_16x16x32_bf16(af[m], bq[n], acc[m][n], 0, 0, 0);
    }
    cur ^= 1;
  }
  __syncthreads();   // done with LDS buffers; reuse [0,32K) for C tile

  const int ba = base[e];
  // write C tile (bf16, relu^2) to LDS; swizzle: byte col*2 ^ ((row>>2)&3)<<5
  {
    char* C = lds;
    const int cg = lane & 15, rq = lane >> 4;
#pragma unroll
    for (int m = 0; m < 4; ++m) {
#pragma unroll
      for (int q = 0; q < 4; ++q) {
        const int row = wr * 64 + m * 16 + rq * 4 + q;
        const int swz = ((row >> 2) & 3) << 5;
#pragma unroll
        for (int n = 0; n < 4; ++n) {
          const int col = wc * 64 + n * 16 + cg;
          float h = acc[m][n][q];
          float rl = fmaxf(h, 0.f);
          *(ushort*)(C + row * 256 + ((col * 2) ^ swz)) = f2bu(rl * rl);
        }
      }
    }
  }
  __syncthreads();
  // coalesced store: 16 lanes cover one 256B row (16B per lane)
  {
    const int u = tid & 15;
#pragma unroll
    for (int p = 0; p < 8; ++p) {
      const int row = p * 16 + (tid >> 4);
      const int gr = m0 + row;
      if (gr < cn) {
        const int swz = ((row >> 2) & 3) << 5;
        uint4 v = *(const uint4*)(lds + row * 256 + ((u * 16) ^ swz));
        *(uint4*)((char*)(hact + (size_t)(ba + gr) * HD + n0) + u * 16) = v;
      }
    }
  }
}

// ---------------------------------------------------------------------------
// Down GEMM: Y[i][n] = sum_h Hact[i][h] * Wdn[n][h]. 128x64 tile, BK=64,
// same staging structure. f32 epilogue (64B segments, already coalesced).
// ---------------------------------------------------------------------------
__global__ __launch_bounds__(256, 3) void k_gemm_dn(
    const bf16* __restrict__ hact, const bf16* __restrict__ wdn,
    const int* __restrict__ cnt, const int* __restrict__ base,
    float* __restrict__ yc)
{
  const int e = blockIdx.z;
  const int cn = cnt[e];
  const int m0 = blockIdx.y * 128;
  if (m0 >= cn) return;
  const int n0 = blockIdx.x * 64;

  // A bufs: [0,16K),[16K,32K); B bufs: [32K,40K),[40K,48K)
  __shared__ char lds[49152];

  const int tid = threadIdx.x;
  const int lane = tid & 63;
  const int wave = tid >> 6;
  const int wr = wave >> 1, wc = wave & 1;
  const int ba = base[e];

  const int c16 = ((lane & 7) ^ (lane >> 3)) * 16;
  const char* apt[4];
  const char* bpt[2];
#pragma unroll
  for (int j = 0; j < 4; ++j) {
    int row = (wave * 4 + j) * 8 + (lane >> 3);
    int ar = m0 + row; if (ar > cn - 1) ar = cn - 1;
    apt[j] = (const char*)(hact + (size_t)(ba + ar) * HD) + c16;
  }
#pragma unroll
  for (int j = 0; j < 2; ++j) {
    int row = (wave * 2 + j) * 8 + (lane >> 3);
    bpt[j] = (const char*)(wdn + (size_t)e * DIMD * HD + (size_t)(n0 + row) * HD) + c16;
  }

  auto stage = [&](int b, int kt) {
    char* la = lds + b * 16384 + (wave * 4) * 1024;
#pragma unroll
    for (int j = 0; j < 4; ++j) gl16(apt[j] + kt * 128, la + j * 1024);
    char* lb = lds + 32768 + b * 8192 + (wave * 2) * 1024;
#pragma unroll
    for (int j = 0; j < 2; ++j) gl16(bpt[j] + kt * 128, lb + j * 1024);
  };

  f32x4 acc[4][2] = {};
  const int koff = lane >> 4;
  const int xr = lane & 7;
  const int fr = lane & 15;

  stage(0, 0);
  const int NT = HD * 2 / 128;  // 48
  int cur = 0;
  for (int kt = 0; kt < NT; ++kt) {
    __syncthreads();
    if (kt + 1 < NT) stage(cur ^ 1, kt + 1);
    const char* Ab = lds + cur * 16384;
    const char* Bc = lds + 32768 + cur * 8192;
#pragma unroll
    for (int ks = 0; ks < 2; ++ks) {
      const int sl = ((ks * 4 + koff) ^ xr) * 16;
      bf16x8 af[4], bq[2];
#pragma unroll
      for (int m = 0; m < 4; ++m)
        af[m] = *(const bf16x8*)(Ab + (wr * 64 + m * 16 + fr) * 128 + sl);
#pragma unroll
      for (int n = 0; n < 2; ++n)
        bq[n] = *(const bf16x8*)(Bc + (wc * 32 + n * 16 + fr) * 128 + sl);
#pragma unroll
      for (int m = 0; m < 4; ++m)
#pragma unroll
        for (int n = 0; n < 2; ++n)
          acc[m][n] = __builtin_amdgcn_mfma_f32_16x16x32_bf16(af[m], bq[n], acc[m][n], 0, 0, 0);
    }
    cur ^= 1;
  }

  const int cg = lane & 15, rq = lane >> 4;
#pragma unroll
  for (int m = 0; m < 4; ++m) {
#pragma unroll
    for (int q = 0; q < 4; ++q) {
      int row = wr * 64 + m * 16 + rq * 4 + q;
      int gr = m0 + row;
      if (gr < cn) {
        float* orow = yc + (size_t)(ba + gr) * DIMD + n0 + wc * 32 + cg;
#pragma unroll
        for (int n = 0; n < 2; ++n) orow[n * 16] = acc[m][n][q];
      }
    }
  }
}

// ---------------------------------------------------------------------------
// Combine: out[t] = w0 * yc[p0] + w1 * yc[p1]
// ---------------------------------------------------------------------------
__global__ __launch_bounds__(192) void k_combine(
    const float* __restrict__ yc, const int* __restrict__ tok_e,
    const int* __restrict__ tok_slot, const float* __restrict__ tok_w,
    const int* __restrict__ base, float* __restrict__ out)
{
  const int t = blockIdx.x;
  const int e0 = tok_e[2 * t], e1 = tok_e[2 * t + 1];
  const int p0 = base[e0] + tok_slot[2 * t];
  const int p1 = base[e1] + tok_slot[2 * t + 1];
  const float w0 = tok_w[2 * t], w1 = tok_w[2 * t + 1];
  const float4* a = (const float4*)(yc + (size_t)p0 * DIMD);
  const float4* b = (const float4*)(yc + (size_t)p1 * DIMD);
  float4* o = (float4*)(out + (size_t)t * DIMD);
  const int i = threadIdx.x;
  float4 va = a[i], vb = b[i];
  o[i] = make_float4(w0 * va.x + w1 * vb.x, w0 * va.y + w1 * vb.y,
                     w0 * va.z + w1 * vb.z, w0 * va.w + w1 * vb.w);
}

// ---------------------------------------------------------------------------
extern "C" void kernel_launch(void* const* d_in, const int* in_sizes, int n_in,
                              void* d_out, int out_size, void* d_ws, size_t ws_size,
                              hipStream_t stream)
{
  const float* x   = (const float*)d_in[0];
  const float* rw  = (const float*)d_in[1];
  const float* sup = (const float*)d_in[2];
  const float* sdn = (const float*)d_in[3];
  const float* rup = (const float*)d_in[4];
  const float* rdn = (const float*)d_in[5];
  float* out = (float*)d_out;

  char* w = (char*)d_ws;
  bf16*  xb       = (bf16*)(w + 0);           //  3,145,728 B
  bf16*  wupT     = (bf16*)(w + 3145728);     // 18,874,368 B
  bf16*  wdn      = (bf16*)(w + 22020096);    // 18,874,368 B
  bf16*  hact     = (bf16*)(w + 40894464);    // 25,165,824 B
  float* yc       = (float*)(w + 66060288);   // 12,582,912 B
  float* probs    = (float*)(w + 78643200);
  float* lse      = (float*)(w + 78675968);
  int*   tok_e    = (int*)(w + 78684160);
  int*   tok_slot = (int*)(w + 78700544);
  float* tok_w    = (float*)(w + 78716928);
  int*   list_tok = (int*)(w + 78733312);
  int*   cnt      = (int*)(w + 78766080);
  int*   base     = (int*)(w + 78766336);

  hipMemsetAsync(cnt, 0, 16, stream);

  k_router<<<512, 256, 0, stream>>>(x, rw, xb, probs, lse, tok_e, tok_slot,
                                    tok_w, list_tok, cnt);
  k_finalize<<<1, 256, 0, stream>>>(probs, lse, cnt, base,
                                    out + (size_t)NTOK * DIMD);
  k_conv_dn<<<dim3(576, 4), 256, 0, stream>>>(sdn, rdn, wdn);
  k_conv_upT<<<dim3(48, 12, 4), 256, 0, stream>>>(sup, rup, wupT);
  k_gemm_up<<<dim3(24, 16, 4), 256, 0, stream>>>(xb, wupT, list_tok, cnt, base, hact);
  k_gemm_dn<<<dim3(12, 16, 4), 256, 0, stream>>>(hact, wdn, cnt, base, yc);
  k_combine<<<2048, 192, 0, stream>>>(yc, tok_e, tok_slot, tok_w, base, out);
}

// Round 3
// 111.479 us; speedup vs baseline: 2.4578x; 1.4043x over previous
//
#include <hip/hip_runtime.h>

// Problem constants
#define NTOK 2048     // B*T
#define DIMD 768
#define HD   3072
#define NE   4

typedef __bf16 bf16;
typedef __bf16 bf16x8 __attribute__((ext_vector_type(8)));
typedef float  f32x4  __attribute__((ext_vector_type(4)));
typedef unsigned int u32;

__device__ inline ushort f2bu(float f) {
  bf16 h = (bf16)f;
  ushort u;
  __builtin_memcpy(&u, &h, 2);
  return u;
}

// async global->LDS, 16B per lane; lds ptr must be wave-uniform
__device__ __forceinline__ void gl16(const void* g, void* l) {
  __builtin_amdgcn_global_load_lds(
      (const __attribute__((address_space(1))) u32*)g,
      (__attribute__((address_space(3))) u32*)l, 16, 0, 0);
}

// ---------------------------------------------------------------------------
// Router: one wave per token. logits(4), softmax, top-2, x->bf16.
// NO atomics (they were 50us of cacheline ping-pong) — lists built by k_build.
// ---------------------------------------------------------------------------
__global__ __launch_bounds__(256) void k_router(
    const float* __restrict__ x, const float* __restrict__ rw,
    bf16* __restrict__ xb,
    float* __restrict__ probs, float* __restrict__ lse,
    int* __restrict__ tok_e, float* __restrict__ tok_w)
{
  const int lane = threadIdx.x & 63;
  const int t = blockIdx.x * 4 + (threadIdx.x >> 6);

  const float4* xr = (const float4*)(x + (size_t)t * DIMD);
  const float4* w0 = (const float4*)(rw);
  const float4* w1 = (const float4*)(rw + DIMD);
  const float4* w2 = (const float4*)(rw + 2 * DIMD);
  const float4* w3 = (const float4*)(rw + 3 * DIMD);

  float a0 = 0.f, a1 = 0.f, a2 = 0.f, a3 = 0.f;
  float4 xv[3];
#pragma unroll
  for (int c = 0; c < 3; ++c) {
    float4 v = xr[lane + 64 * c];
    xv[c] = v;
    float4 q;
    q = w0[lane + 64 * c]; a0 += v.x*q.x + v.y*q.y + v.z*q.z + v.w*q.w;
    q = w1[lane + 64 * c]; a1 += v.x*q.x + v.y*q.y + v.z*q.z + v.w*q.w;
    q = w2[lane + 64 * c]; a2 += v.x*q.x + v.y*q.y + v.z*q.z + v.w*q.w;
    q = w3[lane + 64 * c]; a3 += v.x*q.x + v.y*q.y + v.z*q.z + v.w*q.w;
  }

  bf16* xo = xb + (size_t)t * DIMD;
#pragma unroll
  for (int c = 0; c < 3; ++c) {
    int d = 4 * (lane + 64 * c);
    ushort4 u;
    u.x = f2bu(xv[c].x); u.y = f2bu(xv[c].y);
    u.z = f2bu(xv[c].z); u.w = f2bu(xv[c].w);
    *(ushort4*)(xo + d) = u;
  }

#pragma unroll
  for (int s = 32; s > 0; s >>= 1) {
    a0 += __shfl_xor(a0, s);
    a1 += __shfl_xor(a1, s);
    a2 += __shfl_xor(a2, s);
    a3 += __shfl_xor(a3, s);
  }

  if (lane == 0) {
    float l[4] = {a0, a1, a2, a3};
    float m = fmaxf(fmaxf(l[0], l[1]), fmaxf(l[2], l[3]));
    float p[4];
    float s = 0.f;
#pragma unroll
    for (int e = 0; e < 4; ++e) { p[e] = expf(l[e] - m); s += p[e]; }
    float inv = 1.f / s;
#pragma unroll
    for (int e = 0; e < 4; ++e) p[e] *= inv;

    ((float4*)probs)[t] = make_float4(p[0], p[1], p[2], p[3]);
    lse[t] = m + logf(s);

    int i0 = 0;
#pragma unroll
    for (int e = 1; e < 4; ++e) if (l[e] > l[i0]) i0 = e;
    int i1 = -1;
#pragma unroll
    for (int e = 0; e < 4; ++e)
      if (e != i0 && (i1 < 0 || l[e] > l[i1])) i1 = e;

    float wsum = p[i0] + p[i1];
    tok_e[2 * t]     = i0;
    tok_e[2 * t + 1] = i1;
    tok_w[2 * t]     = p[i0] / wsum;
    tok_w[2 * t + 1] = p[i1] / wsum;
  }
}

// ---------------------------------------------------------------------------
// Build expert lists: deterministic counting sort, single block, no atomics.
// 256 threads x 8 tokens each; int4 histogram + Hillis-Steele LDS scan.
// ---------------------------------------------------------------------------
__global__ __launch_bounds__(256) void k_build(
    const int* __restrict__ tok_e, int* __restrict__ tok_slot,
    int* __restrict__ list_tok, int* __restrict__ cnt, int* __restrict__ base)
{
  __shared__ int4 hist[256];
  const int tid = threadIdx.x;
  const int t0 = tid * 8;

  int ee[16];
  int lh[4] = {0, 0, 0, 0};
#pragma unroll
  for (int i = 0; i < 16; ++i) {
    int e = tok_e[2 * t0 + i];
    ee[i] = e;
    lh[e]++;
  }
  hist[tid] = make_int4(lh[0], lh[1], lh[2], lh[3]);
  __syncthreads();
  for (int s = 1; s < 256; s <<= 1) {
    int4 v = hist[tid];
    int4 u = make_int4(0, 0, 0, 0);
    if (tid >= s) u = hist[tid - s];
    __syncthreads();
    hist[tid] = make_int4(v.x + u.x, v.y + u.y, v.z + u.z, v.w + u.w);
    __syncthreads();
  }
  const int4 tot = hist[255];
  const int4 incl = hist[tid];
  int run[4];
  run[0] = incl.x - lh[0];
  run[1] = incl.y - lh[1];
  run[2] = incl.z - lh[2];
  run[3] = incl.w - lh[3];

#pragma unroll
  for (int i = 0; i < 16; ++i) {
    int e = ee[i];
    int s = run[e]++;
    tok_slot[2 * t0 + i] = s;
    list_tok[e * NTOK + s] = t0 + (i >> 1);
  }

  if (tid == 0) {
    cnt[0] = tot.x; cnt[1] = tot.y; cnt[2] = tot.z; cnt[3] = tot.w;
    base[0] = 0;
    base[1] = tot.x;
    base[2] = tot.x + tot.y;
    base[3] = tot.x + tot.y + tot.z;
  }
}

// ---------------------------------------------------------------------------
// Finalize: aux losses. Single block.
// ---------------------------------------------------------------------------
__global__ __launch_bounds__(256) void k_finalize(
    const float* __restrict__ probs, const float* __restrict__ lse,
    const int* __restrict__ cnt, float* __restrict__ out_tail)
{
  __shared__ float red[256];
  const int tid = threadIdx.x;
  float s0 = 0, s1 = 0, s2 = 0, s3 = 0, sz = 0;
  for (int t = tid; t < NTOK; t += 256) {
    float4 p = ((const float4*)probs)[t];
    s0 += p.x; s1 += p.y; s2 += p.z; s3 += p.w;
    float L = lse[t];
    sz += L * L;
  }
  float vals[5] = {s0, s1, s2, s3, sz};
  float res[5];
#pragma unroll
  for (int q = 0; q < 5; ++q) {
    __syncthreads();
    red[tid] = vals[q];
    __syncthreads();
    for (int s = 128; s > 0; s >>= 1) {
      if (tid < s) red[tid] += red[tid + s];
      __syncthreads();
    }
    res[q] = red[0];
  }
  if (tid == 0) {
    float lb = (float)cnt[0] * res[0] + (float)cnt[1] * res[1] +
               (float)cnt[2] * res[2] + (float)cnt[3] * res[3];
    lb *= (float)NE / ((float)NTOK * (float)NTOK);
    out_tail[0] = lb;
    out_tail[1] = res[4] / (float)NTOK;
  }
}

// ---------------------------------------------------------------------------
// W_down combined = bf16(shared_down + routed_down[e]); [e][n=768][h=3072]
// ---------------------------------------------------------------------------
__global__ __launch_bounds__(256) void k_conv_dn(
    const float* __restrict__ sdn, const float* __restrict__ rdn,
    bf16* __restrict__ wdn)
{
  const int e = blockIdx.y;
  const int M = DIMD * HD / 4;
  const float4* s4 = (const float4*)sdn;
  const float4* r4 = (const float4*)(rdn + (size_t)e * DIMD * HD);
  ushort4* o4 = (ushort4*)(wdn + (size_t)e * DIMD * HD);
  for (int i = blockIdx.x * 256 + threadIdx.x; i < M; i += gridDim.x * 256) {
    float4 a = s4[i], b = r4[i];
    ushort4 u;
    u.x = f2bu(a.x + b.x);
    u.y = f2bu(a.y + b.y);
    u.z = f2bu(a.z + b.z);
    u.w = f2bu(a.w + b.w);
    o4[i] = u;
  }
}

// ---------------------------------------------------------------------------
// W_up combined, transposed: wupT[e][n=3072][d=768]
// ---------------------------------------------------------------------------
__global__ __launch_bounds__(256) void k_conv_upT(
    const float* __restrict__ sup, const float* __restrict__ rup,
    bf16* __restrict__ wupT)
{
  __shared__ ushort T[64][72];
  const int e = blockIdx.z;
  const int n0 = blockIdx.x * 64, d0 = blockIdx.y * 64;
  const int tid = threadIdx.x;
  const float* rb = rup + (size_t)e * DIMD * HD;
#pragma unroll
  for (int p = 0; p < 4; ++p) {
    int dl = p * 16 + (tid >> 4);
    int nl = (tid & 15) * 4;
    size_t gi = (size_t)(d0 + dl) * HD + (n0 + nl);
    float4 a = *(const float4*)(sup + gi);
    float4 b = *(const float4*)(rb + gi);
    T[nl + 0][dl] = f2bu(a.x + b.x);
    T[nl + 1][dl] = f2bu(a.y + b.y);
    T[nl + 2][dl] = f2bu(a.z + b.z);
    T[nl + 3][dl] = f2bu(a.w + b.w);
  }
  __syncthreads();
  bf16* ob = wupT + (size_t)e * HD * DIMD;
#pragma unroll
  for (int p = 0; p < 2; ++p) {
    int nl = p * 32 + (tid >> 3);
    int c = (tid & 7) * 8;
    uint4 v = *(const uint4*)&T[nl][c];
    *(uint4*)(ob + (size_t)(n0 + nl) * DIMD + d0 + c) = v;
  }
}

// ---------------------------------------------------------------------------
// Up GEMM: H[i][n] = sum_d X[tok(i)][d] * WupT[n][d]; relu^2 -> bf16 hact.
// 128x128 tile, BK=64, global_load_lds staging, XOR-swizzled ds_read_b128,
// double-buffered, LDS-staged coalesced epilogue.
// ---------------------------------------------------------------------------
__global__ __launch_bounds__(256, 2) void k_gemm_up(
    const bf16* __restrict__ xb, const bf16* __restrict__ wupT,
    const int* __restrict__ list_tok, const int* __restrict__ cnt,
    const int* __restrict__ base, bf16* __restrict__ hact)
{
  const int e = blockIdx.z;
  const int cn = cnt[e];
  const int m0 = blockIdx.y * 128;
  if (m0 >= cn) return;
  const int n0 = blockIdx.x * 128;

  __shared__ char lds[65536];

  const int tid = threadIdx.x;
  const int lane = tid & 63;
  const int wave = tid >> 6;
  const int wr = wave >> 1, wc = wave & 1;

  const bf16* Bb = wupT + (size_t)e * HD * DIMD;

  const int c16 = ((lane & 7) ^ (lane >> 3)) * 16;
  const char* apt[4];
  const char* bpt[4];
#pragma unroll
  for (int j = 0; j < 4; ++j) {
    int row = (wave * 4 + j) * 8 + (lane >> 3);
    int ar = m0 + row; if (ar > cn - 1) ar = cn - 1;
    int tok = list_tok[e * NTOK + ar];
    apt[j] = (const char*)(xb + (size_t)tok * DIMD) + c16;
    bpt[j] = (const char*)(Bb + (size_t)(n0 + row) * DIMD) + c16;
  }

  auto stage = [&](int b, int kt) {
    char* la = lds + b * 32768 + (wave * 4) * 1024;
    char* lb = la + 16384;
#pragma unroll
    for (int j = 0; j < 4; ++j) {
      gl16(apt[j] + kt * 128, la + j * 1024);
      gl16(bpt[j] + kt * 128, lb + j * 1024);
    }
  };

  f32x4 acc[4][4] = {};
  const int koff = lane >> 4;
  const int xr = lane & 7;
  const int fr = lane & 15;

  stage(0, 0);
  const int NT = DIMD * 2 / 128;  // 12
  int cur = 0;
  for (int kt = 0; kt < NT; ++kt) {
    __syncthreads();
    if (kt + 1 < NT) stage(cur ^ 1, kt + 1);
    const char* Ab = lds + cur * 32768;
    const char* Bc = Ab + 16384;
#pragma unroll
    for (int ks = 0; ks < 2; ++ks) {
      const int sl = ((ks * 4 + koff) ^ xr) * 16;
      bf16x8 af[4], bq[4];
#pragma unroll
      for (int m = 0; m < 4; ++m)
        af[m] = *(const bf16x8*)(Ab + (wr * 64 + m * 16 + fr) * 128 + sl);
#pragma unroll
      for (int n = 0; n < 4; ++n)
        bq[n] = *(const bf16x8*)(Bc + (wc * 64 + n * 16 + fr) * 128 + sl);
#pragma unroll
      for (int m = 0; m < 4; ++m)
#pragma unroll
        for (int n = 0; n < 4; ++n)
          acc[m][n] = __builtin_amdgcn_mfma_f32_16x16x32_bf16(af[m], bq[n], acc[m][n], 0, 0, 0);
    }
    cur ^= 1;
  }
  __syncthreads();

  const int ba = base[e];
  {
    char* C = lds;
    const int cg = lane & 15, rq = lane >> 4;
#pragma unroll
    for (int m = 0; m < 4; ++m) {
#pragma unroll
      for (int q = 0; q < 4; ++q) {
        const int row = wr * 64 + m * 16 + rq * 4 + q;
        const int swz = ((row >> 2) & 3) << 5;
#pragma unroll
        for (int n = 0; n < 4; ++n) {
          const int col = wc * 64 + n * 16 + cg;
          float h = acc[m][n][q];
          float rl = fmaxf(h, 0.f);
          *(ushort*)(C + row * 256 + ((col * 2) ^ swz)) = f2bu(rl * rl);
        }
      }
    }
  }
  __syncthreads();
  {
    const int u = tid & 15;
#pragma unroll
    for (int p = 0; p < 8; ++p) {
      const int row = p * 16 + (tid >> 4);
      const int gr = m0 + row;
      if (gr < cn) {
        const int swz = ((row >> 2) & 3) << 5;
        uint4 v = *(const uint4*)(lds + row * 256 + ((u * 16) ^ swz));
        *(uint4*)((char*)(hact + (size_t)(ba + gr) * HD + n0) + u * 16) = v;
      }
    }
  }
}

// ---------------------------------------------------------------------------
// Down GEMM: Y[i][n] = sum_h Hact[i][h] * Wdn[n][h]. 128x64 tile, BK=64.
// ---------------------------------------------------------------------------
__global__ __launch_bounds__(256, 3) void k_gemm_dn(
    const bf16* __restrict__ hact, const bf16* __restrict__ wdn,
    const int* __restrict__ cnt, const int* __restrict__ base,
    float* __restrict__ yc)
{
  const int e = blockIdx.z;
  const int cn = cnt[e];
  const int m0 = blockIdx.y * 128;
  if (m0 >= cn) return;
  const int n0 = blockIdx.x * 64;

  __shared__ char lds[49152];

  const int tid = threadIdx.x;
  const int lane = tid & 63;
  const int wave = tid >> 6;
  const int wr = wave >> 1, wc = wave & 1;
  const int ba = base[e];

  const int c16 = ((lane & 7) ^ (lane >> 3)) * 16;
  const char* apt[4];
  const char* bpt[2];
#pragma unroll
  for (int j = 0; j < 4; ++j) {
    int row = (wave * 4 + j) * 8 + (lane >> 3);
    int ar = m0 + row; if (ar > cn - 1) ar = cn - 1;
    apt[j] = (const char*)(hact + (size_t)(ba + ar) * HD) + c16;
  }
#pragma unroll
  for (int j = 0; j < 2; ++j) {
    int row = (wave * 2 + j) * 8 + (lane >> 3);
    bpt[j] = (const char*)(wdn + (size_t)e * DIMD * HD + (size_t)(n0 + row) * HD) + c16;
  }

  auto stage = [&](int b, int kt) {
    char* la = lds + b * 16384 + (wave * 4) * 1024;
#pragma unroll
    for (int j = 0; j < 4; ++j) gl16(apt[j] + kt * 128, la + j * 1024);
    char* lb = lds + 32768 + b * 8192 + (wave * 2) * 1024;
#pragma unroll
    for (int j = 0; j < 2; ++j) gl16(bpt[j] + kt * 128, lb + j * 1024);
  };

  f32x4 acc[4][2] = {};
  const int koff = lane >> 4;
  const int xr = lane & 7;
  const int fr = lane & 15;

  stage(0, 0);
  const int NT = HD * 2 / 128;  // 48
  int cur = 0;
  for (int kt = 0; kt < NT; ++kt) {
    __syncthreads();
    if (kt + 1 < NT) stage(cur ^ 1, kt + 1);
    const char* Ab = lds + cur * 16384;
    const char* Bc = lds + 32768 + cur * 8192;
#pragma unroll
    for (int ks = 0; ks < 2; ++ks) {
      const int sl = ((ks * 4 + koff) ^ xr) * 16;
      bf16x8 af[4], bq[2];
#pragma unroll
      for (int m = 0; m < 4; ++m)
        af[m] = *(const bf16x8*)(Ab + (wr * 64 + m * 16 + fr) * 128 + sl);
#pragma unroll
      for (int n = 0; n < 2; ++n)
        bq[n] = *(const bf16x8*)(Bc + (wc * 32 + n * 16 + fr) * 128 + sl);
#pragma unroll
      for (int m = 0; m < 4; ++m)
#pragma unroll
        for (int n = 0; n < 2; ++n)
          acc[m][n] = __builtin_amdgcn_mfma_f32_16x16x32_bf16(af[m], bq[n], acc[m][n], 0, 0, 0);
    }
    cur ^= 1;
  }

  const int cg = lane & 15, rq = lane >> 4;
#pragma unroll
  for (int m = 0; m < 4; ++m) {
#pragma unroll
    for (int q = 0; q < 4; ++q) {
      int row = wr * 64 + m * 16 + rq * 4 + q;
      int gr = m0 + row;
      if (gr < cn) {
        float* orow = yc + (size_t)(ba + gr) * DIMD + n0 + wc * 32 + cg;
#pragma unroll
        for (int n = 0; n < 2; ++n) orow[n * 16] = acc[m][n][q];
      }
    }
  }
}

// ---------------------------------------------------------------------------
// Combine: out[t] = w0 * yc[p0] + w1 * yc[p1]
// ---------------------------------------------------------------------------
__global__ __launch_bounds__(192) void k_combine(
    const float* __restrict__ yc, const int* __restrict__ tok_e,
    const int* __restrict__ tok_slot, const float* __restrict__ tok_w,
    const int* __restrict__ base, float* __restrict__ out)
{
  const int t = blockIdx.x;
  const int e0 = tok_e[2 * t], e1 = tok_e[2 * t + 1];
  const int p0 = base[e0] + tok_slot[2 * t];
  const int p1 = base[e1] + tok_slot[2 * t + 1];
  const float w0 = tok_w[2 * t], w1 = tok_w[2 * t + 1];
  const float4* a = (const float4*)(yc + (size_t)p0 * DIMD);
  const float4* b = (const float4*)(yc + (size_t)p1 * DIMD);
  float4* o = (float4*)(out + (size_t)t * DIMD);
  const int i = threadIdx.x;
  float4 va = a[i], vb = b[i];
  o[i] = make_float4(w0 * va.x + w1 * vb.x, w0 * va.y + w1 * vb.y,
                     w0 * va.z + w1 * vb.z, w0 * va.w + w1 * vb.w);
}

// ---------------------------------------------------------------------------
extern "C" void kernel_launch(void* const* d_in, const int* in_sizes, int n_in,
                              void* d_out, int out_size, void* d_ws, size_t ws_size,
                              hipStream_t stream)
{
  const float* x   = (const float*)d_in[0];
  const float* rw  = (const float*)d_in[1];
  const float* sup = (const float*)d_in[2];
  const float* sdn = (const float*)d_in[3];
  const float* rup = (const float*)d_in[4];
  const float* rdn = (const float*)d_in[5];
  float* out = (float*)d_out;

  char* w = (char*)d_ws;
  bf16*  xb       = (bf16*)(w + 0);           //  3,145,728 B
  bf16*  wupT     = (bf16*)(w + 3145728);     // 18,874,368 B
  bf16*  wdn      = (bf16*)(w + 22020096);    // 18,874,368 B
  bf16*  hact     = (bf16*)(w + 40894464);    // 25,165,824 B
  float* yc       = (float*)(w + 66060288);   // 12,582,912 B
  float* probs    = (float*)(w + 78643200);
  float* lse      = (float*)(w + 78675968);
  int*   tok_e    = (int*)(w + 78684160);
  int*   tok_slot = (int*)(w + 78700544);
  float* tok_w    = (float*)(w + 78716928);
  int*   list_tok = (int*)(w + 78733312);
  int*   cnt      = (int*)(w + 78766080);
  int*   base     = (int*)(w + 78766336);

  k_router<<<512, 256, 0, stream>>>(x, rw, xb, probs, lse, tok_e, tok_w);
  k_build<<<1, 256, 0, stream>>>(tok_e, tok_slot, list_tok, cnt, base);
  k_finalize<<<1, 256, 0, stream>>>(probs, lse, cnt, out + (size_t)NTOK * DIMD);
  k_conv_dn<<<dim3(576, 4), 256, 0, stream>>>(sdn, rdn, wdn);
  k_conv_upT<<<dim3(48, 12, 4), 256, 0, stream>>>(sup, rup, wupT);
  k_gemm_up<<<dim3(24, 16, 4), 256, 0, stream>>>(xb, wupT, list_tok, cnt, base, hact);
  k_gemm_dn<<<dim3(12, 16, 4), 256, 0, stream>>>(hact, wdn, cnt, base, yc);
  k_combine<<<2048, 192, 0, stream>>>(yc, tok_e, tok_slot, tok_w, base, out);
}